// Round 5
// baseline (558.663 us; speedup 1.0000x reference)
//
#include <hip/hip_runtime.h>
#include <math.h>

#define BB 512
#define TT 1024
#define NS 50

typedef _Float16 half2_t __attribute__((ext_vector_type(2)));

static __device__ __forceinline__ half2_t pk_h2(float a, float b) {
    auto r = __builtin_amdgcn_cvt_pkrtz(a, b);   // __fp16x2 -> bit-cast for fdot2
    return __builtin_bit_cast(half2_t, r);
}
static __device__ __forceinline__ float wave_max_f(float v) {
    #pragma unroll
    for (int k = 32; k >= 1; k >>= 1) v = fmaxf(v, __shfl_xor(v, k, 64));
    return v;
}
static __device__ __forceinline__ float wave_sum_f(float v) {
    #pragma unroll
    for (int k = 32; k >= 1; k >>= 1) v += __shfl_xor(v, k, 64);
    return v;
}
static __device__ __forceinline__ int wave_sum_i(int v) {
    #pragma unroll
    for (int k = 32; k >= 1; k >>= 1) v += __shfl_xor(v, k, 64);
    return v;
}
// broadcast: every lane reads lane (addr/4)'s value. VGPR->VGPR, no SGPR hazard.
static __device__ __forceinline__ half2_t bperm_h2(int addr, half2_t v) {
    int u = __builtin_amdgcn_ds_bpermute(addr, __builtin_bit_cast(int, v));
    return __builtin_bit_cast(half2_t, u);
}
static __device__ __forceinline__ float bperm_f(int addr, float v) {
    return __int_as_float(__builtin_amdgcn_ds_bpermute(addr, __float_as_int(v)));
}

__global__ __launch_bounds__(128, 1) void crf_nll_kernel(
    const float* __restrict__ feat,    // (B, T, N)
    const float* __restrict__ trans,   // (N, N)
    const int*   __restrict__ tags,    // (B, T)
    const int*   __restrict__ mask,    // (B, T)
    float* __restrict__ out)           // (B,)
{
    const int b    = blockIdx.x;
    const int tid  = threadIdx.x;
    const int w    = tid >> 6;        // wave 0 = forward (alpha), wave 1 = backward (zeta)
    const int lane = tid & 63;
    const int jj   = (lane < NS) ? lane : 0;

    __shared__ float sh_comb[64];
    __shared__ float sh_sc[2];

    // --- bpermute address registers, pinned in VGPRs via opaque v_mov ---
#define INIT_AD(m) int ad##m; asm("v_mov_b32 %0, %1" : "=v"(ad##m) : "i"(8 * (m)));
    INIT_AD(0)  INIT_AD(1)  INIT_AD(2)  INIT_AD(3)  INIT_AD(4)
    INIT_AD(5)  INIT_AD(6)  INIT_AD(7)  INIT_AD(8)  INIT_AD(9)
    INIT_AD(10) INIT_AD(11) INIT_AD(12) INIT_AD(13) INIT_AD(14)
    INIT_AD(15) INIT_AD(16) INIT_AD(17) INIT_AD(18) INIT_AD(19)
    INIT_AD(20) INIT_AD(21) INIT_AD(22) INIT_AD(23) INIT_AD(24)
#undef INIT_AD
    int ad7x; asm("v_mov_b32 %0, %1" : "=v"(ad7x) : "i"(28));  // lane 7 (off tracking)

    // --- E fragments as 25 named packed-f16 regs.
    // fwd (w=0): e_m = (E[2m][j],  E[2m+1][j])  — column j, contraction over i
    // bwd (w=1): e_m = (E[j][2m],  E[j][2m+1])  — row j,    contraction over j'
    // exp(-10000)==0 exactly -> forbidden transitions vanish.
#define INIT_E(m) half2_t e##m; { \
        int r0 = w ? (jj * NS + 2*(m)) : ((2*(m)) * NS + jj); \
        int r1 = r0 + (w ? 1 : NS); \
        float x0 = __expf(trans[r0]); \
        float x1 = __expf(trans[r1]); \
        if (lane >= NS) { x0 = 0.0f; x1 = 0.0f; } \
        e##m = pk_h2(x0, x1); }
    INIT_E(0)  INIT_E(1)  INIT_E(2)  INIT_E(3)  INIT_E(4)
    INIT_E(5)  INIT_E(6)  INIT_E(7)  INIT_E(8)  INIT_E(9)
    INIT_E(10) INIT_E(11) INIT_E(12) INIT_E(13) INIT_E(14)
    INIT_E(15) INIT_E(16) INIT_E(17) INIT_E(18) INIT_E(19)
    INIT_E(20) INIT_E(21) INIT_E(22) INIT_E(23) INIT_E(24)
#undef INIT_E

    // --- sequence length (mask is a prefix of ones); uniform ---
    int cnt = 0;
    for (int t = lane; t < TT; t += 64) cnt += mask[b * TT + t];
    const int len = wave_sum_i(cnt);
    const int tm  = (len - 1) >> 1;          // cut point t*
    const int nst = w ? (len - 1 - tm) : tm; // steps this wave runs

    const float* fb = feat + (size_t)b * TT * NS;

    // --- init recursion value ---
    // fwd: v = alpha[0][j]   = trans[ROOT][j] + feat[0][j]
    // bwd: v = zeta[len-1][j] = trans[j][END] + feat[len-1][j]   (zeta = beta + feat)
    float v;
    if (w == 0) v = (lane < NS) ? (trans[jj] + fb[jj]) : -INFINITY;
    else        v = (lane < NS) ? (trans[jj * NS + 1] + fb[(size_t)(len - 1) * NS + jj])
                                : -INFINITY;
    float off = wave_max_f(v);

    // --- one step (identical body both directions) ---
    auto step = [&](float f) {
        float p = __expf(v - off);
        int pn = __builtin_amdgcn_update_dpp(
            __float_as_int(p), __float_as_int(p), 0xB1, 0xF, 0xF, true);
        half2_t pp = pk_h2(p, __int_as_float(pn));   // even lane 2m: (p_2m, p_2m+1)
#define DOT(acc, m) acc = __builtin_amdgcn_fdot2(bperm_h2(ad##m, pp), e##m, acc, false)
        float s0 = 0.f, s1 = 0.f, s2 = 0.f, s3 = 0.f;
        float s4 = 0.f, s5 = 0.f, s6 = 0.f, s7 = 0.f;
        DOT(s0, 0);  DOT(s1, 1);  DOT(s2, 2);  DOT(s3, 3);
        DOT(s4, 4);  DOT(s5, 5);  DOT(s6, 6);  DOT(s7, 7);
        DOT(s0, 8);  DOT(s1, 9);  DOT(s2, 10); DOT(s3, 11);
        DOT(s4, 12); DOT(s5, 13); DOT(s6, 14); DOT(s7, 15);
        DOT(s0, 16); DOT(s1, 17); DOT(s2, 18); DOT(s3, 19);
        DOT(s4, 20); DOT(s5, 21); DOT(s6, 22); DOT(s7, 23);
        DOT(s0, 24);
#undef DOT
        float s = ((s0 + s1) + (s2 + s3)) + ((s4 + s5) + (s6 + s7));
        v = f + off + __logf(s);              // dead lanes: s==0 -> -inf, stays dead
        off = bperm_f(ad7x, v) + 2.0f;        // lane 7 never -inf; spread bounded
    };

    // virtual step k -> time index: fwd t = 1+k ; bwd t = len-2-k
    // --- depth-8 prefetch in named regs, hand-unrolled x8 ---
    float q0, q1, q2, q3, q4, q5, q6, q7;
    {
        int t0 = w ? (len - 2) : 1;
        int st = w ? -1 : 1;
#define LD(qr, d) { int tl = t0 + st * (d); tl = (tl < 0) ? 0 : ((tl < TT) ? tl : TT - 1); \
                    qr = fb[(size_t)tl * NS + jj]; }
        LD(q0, 0) LD(q1, 1) LD(q2, 2) LD(q3, 3) LD(q4, 4) LD(q5, 5) LD(q6, 6) LD(q7, 7)
#undef LD
    }

#define PF_STEP(qr, d) { \
        float f = qr; \
        int kl = k + 8 + (d); \
        int tl = w ? (len - 2 - kl) : (1 + kl); \
        tl = (tl < 0) ? 0 : ((tl < TT) ? tl : TT - 1); \
        qr = fb[(size_t)tl * NS + jj]; \
        step(f); }

    int k = 0;
    for (; k + 8 <= nst; k += 8) {
        PF_STEP(q0, 0) PF_STEP(q1, 1) PF_STEP(q2, 2) PF_STEP(q3, 3)
        PF_STEP(q4, 4) PF_STEP(q5, 5) PF_STEP(q6, 6) PF_STEP(q7, 7)
    }
#undef PF_STEP
    for (; k < nst; ++k) {                    // tail <8 steps, rows L1-hot
        int tl = w ? (len - 2 - k) : (1 + k);
        step(fb[(size_t)tl * NS + jj]);
    }

    // --- backward wave publishes beta[tm] = zeta[tm] - feat[tm] ---
    if (w == 1) {
        sh_comb[lane] = v - fb[(size_t)tm * NS + jj];   // -inf lanes stay -inf
    }

    // --- gold path score: both waves, stride-128 over t ---
    const int* tb = tags + (size_t)b * TT;
    float sc = 0.0f;
    for (int t2 = tid; t2 < len; t2 += 128) {
        int tg = tb[t2];
        sc += fb[(size_t)t2 * NS + tg];
        if (t2 >= 1) sc += trans[tb[t2 - 1] * NS + tg];
    }
    sc = wave_sum_f(sc);
    if (lane == 0) sh_sc[w] = sc;

    __syncthreads();

    if (w == 0) {
        // log_z = logsumexp_j( alpha[tm][j] + beta[tm][j] )
        float z = v + sh_comb[lane];          // -inf + -inf = -inf: fine
        float M = wave_max_f(z);
        float Z = wave_sum_f(__expf(z - M));
        float log_z = M + __logf(Z);
        if (lane == 0) {
            float sct = sh_sc[0] + sh_sc[1]
                      + trans[tb[0]]                      // trans[ROOT][tag0]
                      + trans[tb[len - 1] * NS + 1];      // trans[tag_last][END]
            out[b] = log_z - sct;
        }
    }
}

extern "C" void kernel_launch(void* const* d_in, const int* in_sizes, int n_in,
                              void* d_out, int out_size, void* d_ws, size_t ws_size,
                              hipStream_t stream) {
    const float* feat  = (const float*)d_in[0];
    const float* trans = (const float*)d_in[1];
    const int*   tags  = (const int*)d_in[2];
    const int*   mask  = (const int*)d_in[3];
    float* out = (float*)d_out;
    crf_nll_kernel<<<dim3(BB), dim3(128), 0, stream>>>(feat, trans, tags, mask, out);
}

// Round 6
// 301.844 us; speedup vs baseline: 1.8508x; 1.8508x over previous
//
#include <hip/hip_runtime.h>
#include <math.h>

#define BB 512
#define TT 1024
#define NS 50

typedef _Float16 half2_t __attribute__((ext_vector_type(2)));

static __device__ __forceinline__ half2_t pk_h2(float a, float b) {
    auto r = __builtin_amdgcn_cvt_pkrtz(a, b);   // __fp16x2 -> bit-cast for fdot2
    return __builtin_bit_cast(half2_t, r);
}
static __device__ __forceinline__ float wave_max_f(float v) {
    #pragma unroll
    for (int k = 32; k >= 1; k >>= 1) v = fmaxf(v, __shfl_xor(v, k, 64));
    return v;
}
static __device__ __forceinline__ float wave_sum_f(float v) {
    #pragma unroll
    for (int k = 32; k >= 1; k >>= 1) v += __shfl_xor(v, k, 64);
    return v;
}
static __device__ __forceinline__ int wave_sum_i(int v) {
    #pragma unroll
    for (int k = 32; k >= 1; k >>= 1) v += __shfl_xor(v, k, 64);
    return v;
}
// v_readlane: broadcast lane L's 32b (a packed half2) to an SGPR
static __device__ __forceinline__ half2_t bcast_h2(half2_t v, int lane) {
    int u = __builtin_amdgcn_readlane(__builtin_bit_cast(int, v), lane);
    return __builtin_bit_cast(half2_t, u);
}

__global__ __launch_bounds__(128, 1) void crf_nll_kernel(
    const float* __restrict__ feat,    // (B, T, N)
    const float* __restrict__ trans,   // (N, N)
    const int*   __restrict__ tags,    // (B, T)
    const int*   __restrict__ mask,    // (B, T)
    float* __restrict__ out)           // (B,)
{
    const int b    = blockIdx.x;
    const int tid  = threadIdx.x;
    const int w    = tid >> 6;        // wave 0 = forward (alpha), wave 1 = backward (zeta)
    const int lane = tid & 63;
    const int jj   = (lane < NS) ? lane : 0;

    __shared__ float sh_comb[64];
    __shared__ float sh_sc[2];

    // --- E fragments as 25 named packed-f16 regs.
    // fwd (w=0): e_m = (E[2m][j],  E[2m+1][j])  — column j, contraction over i
    // bwd (w=1): e_m = (E[j][2m],  E[j][2m+1])  — row j,    contraction over j'
    // exp(-10000)==0 exactly -> forbidden transitions vanish.
#define INIT_E(m) half2_t e##m; { \
        int r0 = w ? (jj * NS + 2*(m)) : ((2*(m)) * NS + jj); \
        int r1 = r0 + (w ? 1 : NS); \
        float x0 = __expf(trans[r0]); \
        float x1 = __expf(trans[r1]); \
        if (lane >= NS) { x0 = 0.0f; x1 = 0.0f; } \
        e##m = pk_h2(x0, x1); }
    INIT_E(0)  INIT_E(1)  INIT_E(2)  INIT_E(3)  INIT_E(4)
    INIT_E(5)  INIT_E(6)  INIT_E(7)  INIT_E(8)  INIT_E(9)
    INIT_E(10) INIT_E(11) INIT_E(12) INIT_E(13) INIT_E(14)
    INIT_E(15) INIT_E(16) INIT_E(17) INIT_E(18) INIT_E(19)
    INIT_E(20) INIT_E(21) INIT_E(22) INIT_E(23) INIT_E(24)
#undef INIT_E

    // --- sequence length (mask is a prefix of ones); uniform ---
    int cnt = 0;
    for (int t = lane; t < TT; t += 64) cnt += mask[b * TT + t];
    const int len = wave_sum_i(cnt);
    const int tm  = (len - 1) >> 1;          // cut point t*
    const int nst = w ? (len - 1 - tm) : tm; // steps this wave runs

    const float* fb = feat + (size_t)b * TT * NS;

    // --- init recursion value ---
    // fwd: v = alpha[0][j]    = trans[ROOT][j] + feat[0][j]
    // bwd: v = zeta[len-1][j] = trans[j][END] + feat[len-1][j]   (zeta = beta + feat)
    float v;
    if (w == 0) v = (lane < NS) ? (trans[jj] + fb[jj]) : -INFINITY;
    else        v = (lane < NS) ? (trans[jj * NS + 1] + fb[(size_t)(len - 1) * NS + jj])
                                : -INFINITY;
    float off = wave_max_f(v);

    // --- one step (identical body both directions) ---
    // Critical structure: ALL 25 readlanes issue first (into 25 distinct SGPRs),
    // sched_barrier(0) fences them from the dots -> one SGPR-forward hazard per
    // step instead of 25 (R4's stall), and no LDS-pipe round trips (R5's stall).
    auto step = [&](float f) {
        float p = __expf(v - off);
        int pn = __builtin_amdgcn_update_dpp(
            __float_as_int(p), __float_as_int(p), 0xB1, 0xF, 0xF, true);
        half2_t pp = pk_h2(p, __int_as_float(pn));   // even lane 2m: (p_2m, p_2m+1)
#define RL(m) half2_t r##m = bcast_h2(pp, 2*(m));
        RL(0)  RL(1)  RL(2)  RL(3)  RL(4)  RL(5)  RL(6)  RL(7)
        RL(8)  RL(9)  RL(10) RL(11) RL(12) RL(13) RL(14) RL(15)
        RL(16) RL(17) RL(18) RL(19) RL(20) RL(21) RL(22) RL(23) RL(24)
#undef RL
        __builtin_amdgcn_sched_barrier(0);
#define DOT(acc, m) acc = __builtin_amdgcn_fdot2(r##m, e##m, acc, false)
        float s0 = 0.f, s1 = 0.f, s2 = 0.f, s3 = 0.f;
        float s4 = 0.f, s5 = 0.f, s6 = 0.f, s7 = 0.f;
        DOT(s0, 0);  DOT(s1, 1);  DOT(s2, 2);  DOT(s3, 3);
        DOT(s4, 4);  DOT(s5, 5);  DOT(s6, 6);  DOT(s7, 7);
        DOT(s0, 8);  DOT(s1, 9);  DOT(s2, 10); DOT(s3, 11);
        DOT(s4, 12); DOT(s5, 13); DOT(s6, 14); DOT(s7, 15);
        DOT(s0, 16); DOT(s1, 17); DOT(s2, 18); DOT(s3, 19);
        DOT(s4, 20); DOT(s5, 21); DOT(s6, 22); DOT(s7, 23);
        DOT(s0, 24);
#undef DOT
        float s = ((s0 + s1) + (s2 + s3)) + ((s4 + s5) + (s6 + s7));
        v = f + off + __logf(s);              // dead lanes: s==0 -> -inf, stays dead
        // off via lane 7 (never -inf); alpha spread bounded, non-accumulating
        off = __int_as_float(__builtin_amdgcn_readlane(__float_as_int(v), 7)) + 2.0f;
    };

    // virtual step k -> time index: fwd t = 1+k ; bwd t = len-2-k
    // --- depth-8 prefetch in named regs, hand-unrolled x8 ---
    float q0, q1, q2, q3, q4, q5, q6, q7;
    {
        int t0 = w ? (len - 2) : 1;
        int st = w ? -1 : 1;
#define LD(qr, d) { int tl = t0 + st * (d); tl = (tl < 0) ? 0 : ((tl < TT) ? tl : TT - 1); \
                    qr = fb[(size_t)tl * NS + jj]; }
        LD(q0, 0) LD(q1, 1) LD(q2, 2) LD(q3, 3) LD(q4, 4) LD(q5, 5) LD(q6, 6) LD(q7, 7)
#undef LD
    }

#define PF_STEP(qr, d) { \
        float f = qr; \
        int kl = k + 8 + (d); \
        int tl = w ? (len - 2 - kl) : (1 + kl); \
        tl = (tl < 0) ? 0 : ((tl < TT) ? tl : TT - 1); \
        qr = fb[(size_t)tl * NS + jj]; \
        step(f); }

    int k = 0;
    for (; k + 8 <= nst; k += 8) {
        PF_STEP(q0, 0) PF_STEP(q1, 1) PF_STEP(q2, 2) PF_STEP(q3, 3)
        PF_STEP(q4, 4) PF_STEP(q5, 5) PF_STEP(q6, 6) PF_STEP(q7, 7)
    }
#undef PF_STEP
    for (; k < nst; ++k) {                    // tail <8 steps, rows L1-hot
        int tl = w ? (len - 2 - k) : (1 + k);
        step(fb[(size_t)tl * NS + jj]);
    }

    // --- backward wave publishes beta[tm] = zeta[tm] - feat[tm] ---
    if (w == 1) {
        sh_comb[lane] = v - fb[(size_t)tm * NS + jj];   // -inf lanes stay -inf
    }

    // --- gold path score: both waves, stride-128 over t ---
    const int* tb = tags + (size_t)b * TT;
    float sc = 0.0f;
    for (int t2 = tid; t2 < len; t2 += 128) {
        int tg = tb[t2];
        sc += fb[(size_t)t2 * NS + tg];
        if (t2 >= 1) sc += trans[tb[t2 - 1] * NS + tg];
    }
    sc = wave_sum_f(sc);
    if (lane == 0) sh_sc[w] = sc;

    __syncthreads();

    if (w == 0) {
        // log_z = logsumexp_j( alpha[tm][j] + beta[tm][j] )
        float z = v + sh_comb[lane];          // -inf + -inf = -inf: fine
        float M = wave_max_f(z);
        float Z = wave_sum_f(__expf(z - M));
        float log_z = M + __logf(Z);
        if (lane == 0) {
            float sct = sh_sc[0] + sh_sc[1]
                      + trans[tb[0]]                      // trans[ROOT][tag0]
                      + trans[tb[len - 1] * NS + 1];      // trans[tag_last][END]
            out[b] = log_z - sct;
        }
    }
}

extern "C" void kernel_launch(void* const* d_in, const int* in_sizes, int n_in,
                              void* d_out, int out_size, void* d_ws, size_t ws_size,
                              hipStream_t stream) {
    const float* feat  = (const float*)d_in[0];
    const float* trans = (const float*)d_in[1];
    const int*   tags  = (const int*)d_in[2];
    const int*   mask  = (const int*)d_in[3];
    float* out = (float*)d_out;
    crf_nll_kernel<<<dim3(BB), dim3(128), 0, stream>>>(feat, trans, tags, mask, out);
}